// Round 1
// baseline (28473.300 us; speedup 1.0000x reference)
//
#include <hip/hip_runtime.h>
#include <cmath>

#define SS 512
#define BB 64
#define II 256
#define HH 1024
#define BH (BB*HH)   // 65536

typedef _Float16 half8 __attribute__((ext_vector_type(8)));
typedef float    floatx4 __attribute__((ext_vector_type(4)));

// ---------------------------------------------------------------------------
// prep_misc: convert X fp32->fp16, zero h buffer 0 (hi+lo), zero counters
// grid 4096 x 256 = 1,048,576 threads
// ---------------------------------------------------------------------------
__global__ void prep_misc(const float* __restrict__ X, _Float16* __restrict__ X16,
                          _Float16* __restrict__ h_hi, _Float16* __restrict__ h_lo,
                          unsigned* __restrict__ counters) {
    const int tid = blockIdx.x * 256 + threadIdx.x;
    const size_t base = (size_t)tid * 8;   // 8 elems/thread covers 8,388,608 exactly
    #pragma unroll
    for (int j = 0; j < 8; ++j) X16[base + j] = (_Float16)X[base + j];
    // zero h buf0: 3*64*1024 halfs = 393,216 B each array -> 49,152 x 8B
    if (tid < 49152) {
        ((unsigned long long*)h_hi)[tid] = 0ULL;
        ((unsigned long long*)h_lo)[tid] = 0ULL;
    }
    if (tid < 128) counters[tid] = 0u;   // karr[48] + arrive (at word 64)
}

// ---------------------------------------------------------------------------
// prep_bpack: pack weight slices into MFMA B-fragment order, fp16.
// One thread per (wg, frag, lane): 192*64*64 = 786,432 -> 3072 x 256.
// Frag layout (16x16x32 f16 B operand): lane holds B[k=(lane>>4)*8+j][n=lane&15],
// j=0..7 contiguous in K.
// ---------------------------------------------------------------------------
__global__ void prep_bpack(const float* __restrict__ Wxh, const float* __restrict__ Whh,
                           const float* __restrict__ Wl,  const float* __restrict__ Ul,
                           _Float16* __restrict__ Bpack) {
    const int tid  = blockIdx.x * 256 + threadIdx.x;
    const int w    = tid >> 12;         // workgroup id 0..191
    const int r    = tid & 4095;
    const int f    = r >> 6;            // frag 0..63
    const int lane = r & 63;
    const int layer = w >> 6;
    const int rem   = w & 63;
    const int g     = rem >> 2;         // n-group 0..15
    const int s     = rem & 3;          // k-slice 0..3
    const int kstep = f >> 2;
    const int tt    = f & 3;
    const int n  = g * 64 + tt * 16 + (lane & 15);
    const int kq = (lane >> 4) * 8;
    const float* src;
    int k;
    if (layer == 0) {
        if (kstep >= 10) return;        // layer0 only has 10 k-steps (2 X + 8 h0)
        if (kstep < 2) { src = Wxh; k = s * 64  + kstep * 32 + kq; }
        else           { src = Whh; k = s * 256 + (kstep - 2) * 32 + kq; }
    } else {
        const int li = layer - 1;
        if (kstep < 8) { src = Ul + (size_t)li * HH * HH; k = s * 256 + kstep * 32 + kq; }
        else           { src = Wl + (size_t)li * HH * HH; k = s * 256 + (kstep - 8) * 32 + kq; }
    }
    _Float16* dst = Bpack + (size_t)w * 32768 + (size_t)f * 512 + (size_t)lane * 8;
    #pragma unroll
    for (int j = 0; j < 8; ++j) dst[j] = (_Float16)src[(size_t)(k + j) * HH + n];
}

// ---------------------------------------------------------------------------
// Persistent RNN kernel. 192 WGs x 256 threads, all co-resident.
// WG = (layer 0..2) x (n-group 0..15, 64 cols) x (k-slice 0..3).
// Per step: MFMA partial GEMM -> last-arrival finalize (sum, bias, tanh,
// write h hi/lo + outputs) -> global arrive barrier.
// ---------------------------------------------------------------------------
__global__ __launch_bounds__(256, 1) void rnn_persist(
        const _Float16* __restrict__ X16,
        const _Float16* __restrict__ Bpack,
        _Float16* __restrict__ h_hi,   // [2][3][B][H]
        _Float16* __restrict__ h_lo,
        float* __restrict__ partials,  // [48][4][4 waves][4 tt][64 lanes][4]
        unsigned* __restrict__ karr,   // [48] monotonic
        unsigned* __restrict__ arrive, // [1]  monotonic
        const float* __restrict__ b_h,
        const float* __restrict__ b_layers,
        float* __restrict__ out) {

    const int layer = blockIdx.x >> 6;
    const int rem   = blockIdx.x & 63;
    const int g     = rem >> 2;
    const int s     = rem & 3;
    const int group = layer * 16 + g;

    const int tid  = threadIdx.x;
    const int wave = tid >> 6;
    const int lane = tid & 63;
    const int rowm = wave * 16 + (lane & 15);   // batch row 0..63
    const int kq   = (lane >> 4) * 8;
    const int n0   = g * 64;

    // ---- stage this WG's weight slice into LDS (frag-packed, 64 KB) ----
    __shared__ __align__(16) _Float16 Bs[64 * 512];
    {
        const uint4* src = (const uint4*)(Bpack + (size_t)blockIdx.x * 32768);
        uint4* dst = (uint4*)Bs;
        for (int i = tid; i < 4096; i += 256) dst[i] = src[i];
    }
    __syncthreads();

    __shared__ unsigned sflag;

    for (int t = 0; t < SS; ++t) {
        const int rb = t & 1;
        const _Float16* hi = h_hi + (size_t)rb * 3 * BH;
        const _Float16* lo = h_lo + (size_t)rb * 3 * BH;
        _Float16* nhi = h_hi + (size_t)(rb ^ 1) * 3 * BH;
        _Float16* nlo = h_lo + (size_t)(rb ^ 1) * 3 * BH;

        floatx4 acc[4];
        #pragma unroll
        for (int tt = 0; tt < 4; ++tt) acc[tt] = (floatx4){0.f, 0.f, 0.f, 0.f};

        int ksg = 0;
        auto do_seg = [&](const _Float16* Ahi, const _Float16* Alo,
                          int astride, int kbase, int nsteps) {
            const size_t rowoff = (size_t)rowm * astride + kbase + kq;
            for (int ks = 0; ks < nsteps; ++ks) {
                const half8 a = *(const half8*)(Ahi + rowoff + ks * 32);
                half8 al;
                if (Alo) al = *(const half8*)(Alo + rowoff + ks * 32);
                #pragma unroll
                for (int tt = 0; tt < 4; ++tt) {
                    const half8 bb = *(const half8*)(&Bs[(ksg * 4 + tt) * 512 + lane * 8]);
                    acc[tt] = __builtin_amdgcn_mfma_f32_16x16x32_f16(a, bb, acc[tt], 0, 0, 0);
                    if (Alo)
                        acc[tt] = __builtin_amdgcn_mfma_f32_16x16x32_f16(al, bb, acc[tt], 0, 0, 0);
                }
                ++ksg;
            }
        };

        if (layer == 0) {
            do_seg(X16 + (size_t)t * BB * II, nullptr, II, s * 64, 2);
            do_seg(hi + 0 * BH, lo + 0 * BH, HH, s * 256, 8);
        } else if (layer == 1) {
            do_seg(hi + 1 * BH, lo + 1 * BH, HH, s * 256, 8);
            do_seg(hi + 0 * BH, lo + 0 * BH, HH, s * 256, 8);
        } else {
            do_seg(hi + 2 * BH, lo + 2 * BH, HH, s * 256, 8);
            do_seg(hi + 1 * BH, lo + 1 * BH, HH, s * 256, 8);
        }

        // ---- store fp32 partial tile (frag-packed) ----
        {
            float* pb = partials + ((((size_t)group * 4 + s) * 4 + wave) * 4) * 256;
            #pragma unroll
            for (int tt = 0; tt < 4; ++tt)
                *(floatx4*)(pb + tt * 256 + lane * 4) = acc[tt];
        }

        __syncthreads();
        if (tid == 0) {
            __threadfence();
            const unsigned old = __hip_atomic_fetch_add(&karr[group], 1u,
                                      __ATOMIC_ACQ_REL, __HIP_MEMORY_SCOPE_AGENT);
            __threadfence();
            sflag = (old == (unsigned)(4 * t + 3)) ? 1u : 0u;
        }
        __syncthreads();

        if (sflag) {
            // ---- finalize: sum 4 k-slices, bias, tanh, write h hi/lo (+out) ----
            const float* bias = (layer == 0) ? b_h : (b_layers + (size_t)(layer - 1) * HH);
            const float* pg = partials + (size_t)group * 4 * 4 * 4 * 256;
            #pragma unroll
            for (int tt = 0; tt < 4; ++tt) {
                floatx4 sum = (floatx4){0.f, 0.f, 0.f, 0.f};
                #pragma unroll
                for (int s2 = 0; s2 < 4; ++s2)
                    sum += *(const floatx4*)(pg + (((size_t)s2 * 4 + wave) * 4 + tt) * 256 + lane * 4);
                const int n  = n0 + tt * 16 + (lane & 15);
                const float bv = bias[n];
                const int mb = wave * 16 + (lane >> 4) * 4;
                #pragma unroll
                for (int rr = 0; rr < 4; ++rr) {
                    const float v = tanhf(sum[rr] + bv);
                    const int m = mb + rr;
                    const size_t hoff = (size_t)layer * BH + (size_t)m * HH + n;
                    const _Float16 vh = (_Float16)v;
                    nhi[hoff] = vh;
                    nlo[hoff] = (_Float16)(v - (float)vh);
                    if (layer == 2) out[(size_t)t * BH + (size_t)m * HH + n] = v;
                    if (t == SS - 1)
                        out[(size_t)SS * BH + (size_t)layer * BH + (size_t)m * HH + n] = v;
                }
            }
            __syncthreads();
        }

        // ---- global barrier (one per step) ----
        if (tid == 0) {
            __threadfence();
            __hip_atomic_fetch_add(arrive, 1u, __ATOMIC_RELEASE, __HIP_MEMORY_SCOPE_AGENT);
            const unsigned target = (unsigned)(192 * (t + 1));
            while (__hip_atomic_load(arrive, __ATOMIC_ACQUIRE, __HIP_MEMORY_SCOPE_AGENT) < target)
                __builtin_amdgcn_s_sleep(2);
            __threadfence();
        }
        __syncthreads();
    }
}

// ---------------------------------------------------------------------------
extern "C" void kernel_launch(void* const* d_in, const int* in_sizes, int n_in,
                              void* d_out, int out_size, void* d_ws, size_t ws_size,
                              hipStream_t stream) {
    (void)in_sizes; (void)n_in; (void)out_size; (void)ws_size;
    const float* X   = (const float*)d_in[0];
    const float* Wxh = (const float*)d_in[1];
    const float* Whh = (const float*)d_in[2];
    const float* bh  = (const float*)d_in[3];
    const float* Wl  = (const float*)d_in[4];
    const float* Ul  = (const float*)d_in[5];
    const float* bl  = (const float*)d_in[6];
    float* out = (float*)d_out;

    char* ws = (char*)d_ws;
    _Float16* X16   = (_Float16*)(ws);                                   // 16,777,216 B
    _Float16* Bpack = (_Float16*)(ws + 16777216);                        // 12,582,912 B
    _Float16* h_hi  = (_Float16*)(ws + 16777216 + 12582912);             //    786,432 B
    _Float16* h_lo  = (_Float16*)(ws + 16777216 + 12582912 + 786432);    //    786,432 B
    float* partials = (float*)(ws + 16777216 + 12582912 + 2 * 786432);   //  3,145,728 B
    unsigned* ctrs  = (unsigned*)(ws + 16777216 + 12582912 + 2 * 786432 + 3145728); // 512 B

    hipLaunchKernelGGL(prep_misc,  dim3(4096), dim3(256), 0, stream, X, X16, h_hi, h_lo, ctrs);
    hipLaunchKernelGGL(prep_bpack, dim3(3072), dim3(256), 0, stream, Wxh, Whh, Wl, Ul, Bpack);
    hipLaunchKernelGGL(rnn_persist, dim3(192), dim3(256), 0, stream,
                       X16, Bpack, h_hi, h_lo, partials, ctrs, ctrs + 64, bh, bl, out);
}

// Round 2
// 14683.612 us; speedup vs baseline: 1.9391x; 1.9391x over previous
//
#include <hip/hip_runtime.h>
#include <cmath>

#define SS 512
#define BB 64
#define II 256
#define HH 1024
#define BH (BB*HH)   // 65536

typedef _Float16 half8 __attribute__((ext_vector_type(8)));
typedef float    floatx4 __attribute__((ext_vector_type(4)));

// ---------------------------------------------------------------------------
// prep_misc: convert X fp32->fp16, zero h buffer 0 (hi+lo), zero flags/epoch
// grid 4096 x 256 = 1,048,576 threads
// ---------------------------------------------------------------------------
__global__ void prep_misc(const float* __restrict__ X, _Float16* __restrict__ X16,
                          _Float16* __restrict__ h_hi, _Float16* __restrict__ h_lo,
                          unsigned* __restrict__ flags) {
    const int tid = blockIdx.x * 256 + threadIdx.x;
    const size_t base = (size_t)tid * 8;   // 8 elems/thread covers 8,388,608 exactly
    #pragma unroll
    for (int j = 0; j < 8; ++j) X16[base + j] = (_Float16)X[base + j];
    // zero h buf0: 3*64*1024 halfs = 393,216 B each array -> 49,152 x 8B
    if (tid < 49152) {
        ((unsigned long long*)h_hi)[tid] = 0ULL;
        ((unsigned long long*)h_lo)[tid] = 0ULL;
    }
    if (tid < 256) flags[tid] = 0u;   // flags[0..191], epoch at [192]
}

// ---------------------------------------------------------------------------
// prep_bpack: pack per-WG weight slices into MFMA B-fragment order, fp16.
// New partition: WG w = (layer = w>>6) x (n-group g = w&63, 16 cols), full K.
// Frag f = k-step (32 K per frag). Layer0: f 0..7 = Wxh, 8..39 = Whh (40 frags).
// Layer l>=1: f 0..31 = U_{l-1}, 32..63 = W_{l-1} (64 frags).
// Frag layout (16x16x32 f16 B operand): lane holds B[k=(lane>>4)*8+j][n=lane&15].
// One thread per (w, f, lane): 192*64*64 = 786,432 -> 3072 x 256.
// ---------------------------------------------------------------------------
__global__ void prep_bpack(const float* __restrict__ Wxh, const float* __restrict__ Whh,
                           const float* __restrict__ Wl,  const float* __restrict__ Ul,
                           _Float16* __restrict__ Bpack) {
    const int tid  = blockIdx.x * 256 + threadIdx.x;
    const int w    = tid >> 12;         // workgroup id 0..191
    const int r    = tid & 4095;
    const int f    = r >> 6;            // frag 0..63
    const int lane = r & 63;
    const int layer = w >> 6;
    const int g     = w & 63;
    const int n  = g * 16 + (lane & 15);
    const int kq = (lane >> 4) * 8;
    const float* src;
    int k;
    if (layer == 0) {
        if (f >= 40) return;            // layer0: 8 X-frags + 32 Whh-frags
        if (f < 8) { src = Wxh; k = f * 32 + kq; }
        else       { src = Whh; k = (f - 8) * 32 + kq; }
    } else {
        const int li = layer - 1;
        if (f < 32) { src = Ul + (size_t)li * HH * HH; k = f * 32 + kq; }
        else        { src = Wl + (size_t)li * HH * HH; k = (f - 32) * 32 + kq; }
    }
    _Float16* dst = Bpack + (size_t)w * 32768 + (size_t)f * 512 + (size_t)lane * 8;
    #pragma unroll
    for (int j = 0; j < 8; ++j) dst[j] = (_Float16)src[(size_t)(k + j) * HH + n];
}

// ---------------------------------------------------------------------------
// Persistent RNN kernel. 192 WGs x 256 threads, all co-resident (<=256 CUs).
// WG = (layer 0..2) x (n-group 0..63, 16 cols), FULL K -> no cross-WG reduce.
// Per step: MFMA -> bias+tanh -> write h hi/lo (+out) -> flag/epoch barrier.
// ---------------------------------------------------------------------------
__global__ __launch_bounds__(256, 1) void rnn_persist(
        const _Float16* __restrict__ X16,
        const _Float16* __restrict__ Bpack,
        _Float16* __restrict__ h_hi,   // [2][3][B][H]
        _Float16* __restrict__ h_lo,
        unsigned* __restrict__ flags,  // [192] monotonic step counters
        unsigned* __restrict__ epoch,  // [1]   monotonic
        const float* __restrict__ b_h,
        const float* __restrict__ b_layers,
        float* __restrict__ out) {

    const int wgid  = blockIdx.x;
    const int layer = wgid >> 6;
    const int g     = wgid & 63;
    const int n0    = g * 16;

    const int tid  = threadIdx.x;
    const int wave = tid >> 6;
    const int lane = tid & 63;
    const int rowm = wave * 16 + (lane & 15);   // batch row 0..63
    const int kq   = (lane >> 4) * 8;

    // ---- stage this WG's weight slice into LDS (frag-packed, <=64 KB) ----
    __shared__ __align__(16) _Float16 Bs[64 * 512];
    {
        const int nvec = (layer == 0) ? 40 * 64 : 64 * 64;   // uint4s
        const uint4* src = (const uint4*)(Bpack + (size_t)wgid * 32768);
        uint4* dst = (uint4*)Bs;
        for (int i = tid; i < nvec; i += 256) dst[i] = src[i];
    }
    __syncthreads();

    const float bv = (layer == 0) ? b_h[n0 + (lane & 15)]
                                  : b_layers[(size_t)(layer - 1) * HH + n0 + (lane & 15)];

    for (int t = 0; t < SS; ++t) {
        const int rb = t & 1;
        const _Float16* hi = h_hi + (size_t)rb * 3 * BH;
        const _Float16* lo = h_lo + (size_t)rb * 3 * BH;
        _Float16* nhi = h_hi + (size_t)(rb ^ 1) * 3 * BH;
        _Float16* nlo = h_lo + (size_t)(rb ^ 1) * 3 * BH;

        floatx4 accH = (floatx4){0.f, 0.f, 0.f, 0.f};
        floatx4 accL = (floatx4){0.f, 0.f, 0.f, 0.f};

        int ksg = 0;
        auto do_seg = [&](const _Float16* Ahi, const _Float16* Alo,
                          int astride, int nsteps) {
            const size_t rowoff = (size_t)rowm * astride + kq;
            #pragma unroll 8
            for (int ks = 0; ks < nsteps; ++ks) {
                const half8 a  = *(const half8*)(Ahi + rowoff + ks * 32);
                const half8 bb = *(const half8*)(&Bs[(ksg + ks) * 512 + lane * 8]);
                accH = __builtin_amdgcn_mfma_f32_16x16x32_f16(a, bb, accH, 0, 0, 0);
                if (Alo) {
                    const half8 al = *(const half8*)(Alo + rowoff + ks * 32);
                    accL = __builtin_amdgcn_mfma_f32_16x16x32_f16(al, bb, accL, 0, 0, 0);
                }
            }
            ksg += nsteps;
        };

        if (layer == 0) {
            do_seg(X16 + (size_t)t * BB * II, nullptr, II, 8);
            do_seg(hi + 0 * BH, lo + 0 * BH, HH, 32);
        } else if (layer == 1) {
            do_seg(hi + 1 * BH, lo + 1 * BH, HH, 32);
            do_seg(hi + 0 * BH, lo + 0 * BH, HH, 32);
        } else {
            do_seg(hi + 2 * BH, lo + 2 * BH, HH, 32);
            do_seg(hi + 1 * BH, lo + 1 * BH, HH, 32);
        }

        // ---- finalize own 64x16 tile: bias, tanh, write h hi/lo (+ out) ----
        {
            const int n  = n0 + (lane & 15);
            const int mb = wave * 16 + (lane >> 4) * 4;
            #pragma unroll
            for (int rr = 0; rr < 4; ++rr) {
                const float v = tanhf(accH[rr] + accL[rr] + bv);
                const int m = mb + rr;
                const size_t hoff = (size_t)layer * BH + (size_t)m * HH + n;
                const _Float16 vh = (_Float16)v;
                nhi[hoff] = vh;
                nlo[hoff] = (_Float16)(v - (float)vh);
                if (layer == 2) out[(size_t)t * BH + (size_t)m * HH + n] = v;
                if (t == SS - 1)
                    out[(size_t)SS * BH + (size_t)layer * BH + (size_t)m * HH + n] = v;
            }
        }

        // ---- device barrier: flag (release) -> WG0 gathers -> epoch ----
        __syncthreads();
        if (tid == 0)
            __hip_atomic_store(&flags[wgid], (unsigned)(t + 1),
                               __ATOMIC_RELEASE, __HIP_MEMORY_SCOPE_AGENT);
        if (wgid == 0) {
            if (tid < 192) {
                while (__hip_atomic_load(&flags[tid], __ATOMIC_RELAXED,
                                         __HIP_MEMORY_SCOPE_AGENT) < (unsigned)(t + 1))
                    __builtin_amdgcn_s_sleep(1);
            }
            __syncthreads();
            if (tid == 0) {
                __builtin_amdgcn_fence(__ATOMIC_ACQUIRE, "agent");
                __hip_atomic_store(epoch, (unsigned)(t + 1),
                                   __ATOMIC_RELEASE, __HIP_MEMORY_SCOPE_AGENT);
            }
        } else {
            if (tid == 0) {
                while (__hip_atomic_load(epoch, __ATOMIC_RELAXED,
                                         __HIP_MEMORY_SCOPE_AGENT) < (unsigned)(t + 1))
                    __builtin_amdgcn_s_sleep(2);
            }
        }
        __syncthreads();
        __builtin_amdgcn_fence(__ATOMIC_ACQUIRE, "agent");
    }
}

// ---------------------------------------------------------------------------
extern "C" void kernel_launch(void* const* d_in, const int* in_sizes, int n_in,
                              void* d_out, int out_size, void* d_ws, size_t ws_size,
                              hipStream_t stream) {
    (void)in_sizes; (void)n_in; (void)out_size; (void)ws_size;
    const float* X   = (const float*)d_in[0];
    const float* Wxh = (const float*)d_in[1];
    const float* Whh = (const float*)d_in[2];
    const float* bh  = (const float*)d_in[3];
    const float* Wl  = (const float*)d_in[4];
    const float* Ul  = (const float*)d_in[5];
    const float* bl  = (const float*)d_in[6];
    float* out = (float*)d_out;

    char* ws = (char*)d_ws;
    _Float16* X16   = (_Float16*)(ws);                                   // 16,777,216 B
    _Float16* Bpack = (_Float16*)(ws + 16777216);                        // 12,582,912 B
    _Float16* h_hi  = (_Float16*)(ws + 16777216 + 12582912);             //    786,432 B
    _Float16* h_lo  = (_Float16*)(ws + 16777216 + 12582912 + 786432);    //    786,432 B
    unsigned* flags = (unsigned*)(ws + 16777216 + 12582912 + 2 * 786432); //    1,024 B

    hipLaunchKernelGGL(prep_misc,  dim3(4096), dim3(256), 0, stream, X, X16, h_hi, h_lo, flags);
    hipLaunchKernelGGL(prep_bpack, dim3(3072), dim3(256), 0, stream, Wxh, Whh, Wl, Ul, Bpack);
    hipLaunchKernelGGL(rnn_persist, dim3(192), dim3(256), 0, stream,
                       X16, Bpack, h_hi, h_lo, flags, flags + 192, bh, bl, out);
}